// Round 1
// baseline (228.202 us; speedup 1.0000x reference)
//
#include <hip/hip_runtime.h>
#include <stdint.h>

#define D_MODEL 1024
#define D_STATE 16
#define BB 4
#define TT 2048
#define MM (BB*TT)       /* 8192 rows */
#define NCH 64           /* time chunks */
#define CL (TT/NCH)      /* 32 steps per chunk */

typedef __attribute__((ext_vector_type(4))) float f32x4;
typedef __attribute__((ext_vector_type(8))) short short8;

__device__ __forceinline__ unsigned short f2bf(float f) {
  union { float f; uint32_t u; } v; v.f = f;
  uint32_t r = v.u + 0x7FFFu + ((v.u >> 16) & 1u);   // RNE
  return (unsigned short)(r >> 16);
}

__device__ __forceinline__ float softplusf(float v) {
  return v > 20.f ? v : log1pf(expf(v));
}

// ---------------- f32 -> bf16 conversion (float4 vectorized) ----------------
__global__ __launch_bounds__(256) void cvt_bf16_kernel(
    const float* __restrict__ in, unsigned short* __restrict__ out, int n4)
{
  const float4* in4 = (const float4*)in;
  ushort4* out4 = (ushort4*)out;
  int i = blockIdx.x * blockDim.x + threadIdx.x;
  const int stride = gridDim.x * blockDim.x;
  for (; i < n4; i += stride) {
    float4 v = in4[i];
    ushort4 o;
    o.x = f2bf(v.x); o.y = f2bf(v.y); o.z = f2bf(v.z); o.w = f2bf(v.w);
    out4[i] = o;
  }
}

// ---------------- bf16 GEMM, B^T layout: C[m][n] = sum_k A[m][k]*B[n][k] ----
// m97 structure: 128x128 tile, BK=32, global_load_lds width 16,
// 4 waves in 2x2, each computes 64x64 via 4x4 fragments of 16x16x32 MFMA.
template<bool SOFTPLUS>
__global__ __launch_bounds__(256) void gemm_bt_kernel(
    const unsigned short* __restrict__ A,   // M x K bf16 (row-major)
    const unsigned short* __restrict__ Bm,  // N x K bf16 (row-major, i.e. B^T)
    const float* __restrict__ bias,         // N
    float* __restrict__ C,                  // M x N f32
    int M, int N, int K)
{
  __shared__ __align__(16) unsigned short Alds[128*32];
  __shared__ __align__(16) unsigned short Blds[128*32];
  const int tid  = threadIdx.x;
  const int lane = tid & 63;
  const int w    = tid >> 6;          // wave 0..3
  const int wr   = w >> 1, wc = w & 1;
  const int bm   = blockIdx.y * 128;
  const int bn   = blockIdx.x * 128;
  const int r16  = lane & 15, kh = lane >> 4;

  f32x4 acc[4][4] = {};

  for (int k0 = 0; k0 < K; k0 += 32) {
    __syncthreads();   // protect LDS from previous iteration's readers
    #pragma unroll
    for (int r = 0; r < 2; ++r) {
      const int base = r*4096 + w*1024;          // wave-uniform LDS byte base
      const int F    = base + lane*16;           // per-lane flat byte offset
      const int row  = F >> 6;                   // 64B per tile row (32 bf16)
      const int colb = F & 63;
      const char* ga = (const char*)A  + (((size_t)(bm + row))*K + k0)*2 + colb;
      const char* gb = (const char*)Bm + (((size_t)(bn + row))*K + k0)*2 + colb;
      __builtin_amdgcn_global_load_lds(
          (const __attribute__((address_space(1))) void*)ga,
          (__attribute__((address_space(3))) void*)((char*)Alds + base), 16, 0, 0);
      __builtin_amdgcn_global_load_lds(
          (const __attribute__((address_space(1))) void*)gb,
          (__attribute__((address_space(3))) void*)((char*)Blds + base), 16, 0, 0);
    }
    __syncthreads();   // drains vmcnt -> tiles visible

    short8 af[4], bf[4];
    #pragma unroll
    for (int m = 0; m < 4; ++m)
      af[m] = *(const short8*)&Alds[(wr*64 + m*16 + r16)*32 + kh*8];
    #pragma unroll
    for (int n = 0; n < 4; ++n)
      bf[n] = *(const short8*)&Blds[(wc*64 + n*16 + r16)*32 + kh*8];
    #pragma unroll
    for (int m = 0; m < 4; ++m)
      #pragma unroll
      for (int n = 0; n < 4; ++n)
        acc[m][n] = __builtin_amdgcn_mfma_f32_16x16x32_bf16(af[m], bf[n], acc[m][n], 0, 0, 0);
  }

  // epilogue: C[row][col] ; row = bm + wr*64 + m*16 + kh*4 + j ; col = bn + wc*64 + n*16 + r16
  #pragma unroll
  for (int n = 0; n < 4; ++n) {
    const int col = bn + wc*64 + n*16 + r16;
    const float bv = bias[col];
    #pragma unroll
    for (int m = 0; m < 4; ++m) {
      #pragma unroll
      for (int j = 0; j < 4; ++j) {
        const int row = bm + wr*64 + m*16 + kh*4 + j;
        float v = acc[m][n][j] + bv;
        if (SOFTPLUS) v = softplusf(v);
        C[(size_t)row*N + col] = v;
      }
    }
  }
}

// ---------------- scan pass 1: per-chunk local state L and sum(dt) ----------
// thread = (b, chunk, e); lanes consecutive in e -> coalesced.
__global__ __launch_bounds__(256) void scan_pass1_kernel(
    const float* __restrict__ x, const float* __restrict__ delta,
    const float* __restrict__ a_log,
    float* __restrict__ Lc, float* __restrict__ dts_out)
{
  const int e  = blockIdx.x * 256 + threadIdx.x;
  const int bc = blockIdx.y;
  const int b  = bc >> 6;            // NCH = 64
  const int c  = bc & (NCH-1);

  float c2[D_STATE];
  #pragma unroll
  for (int s = 0; s < D_STATE; ++s) {
    const float ap = softplusf(a_log[e*D_STATE + s]) + 1e-4f;
    c2[s] = -ap * 1.44269504088896f;   // -a_pos * log2(e)
  }
  const size_t base = ((size_t)b*TT + (size_t)c*CL)*D_MODEL + e;
  const float* xp = x + base;
  const float* dp = delta + base;
  float S[D_STATE] = {};
  float dts = 0.f;
  for (int t = 0; t < CL; ++t) {
    const float dt = dp[(size_t)t*D_MODEL];
    const float xv = xp[(size_t)t*D_MODEL];
    dts += dt;
    const float u = dt * xv;
    #pragma unroll
    for (int s = 0; s < D_STATE; ++s)
      S[s] = exp2f(c2[s]*dt) * S[s] + u;
  }
  const size_t ci = ((size_t)c*BB + b)*D_MODEL + e;
  dts_out[ci] = dts;
  float4* Lp = (float4*)&Lc[ci*D_STATE];
  #pragma unroll
  for (int q = 0; q < 4; ++q)
    Lp[q] = make_float4(S[q*4+0], S[q*4+1], S[q*4+2], S[q*4+3]);
}

// ---------------- scan pass 2: in-place exclusive scan over chunks ----------
// thread = (b, e, s). After this, Lc holds the chunk's INITIAL state.
__global__ __launch_bounds__(256) void scan_pass2_kernel(
    const float* __restrict__ a_log,
    float* __restrict__ Lc, const float* __restrict__ dts)
{
  const int tid = blockIdx.x * 256 + threadIdx.x;  // < 65536
  const int s = tid & 15;
  const int e = (tid >> 4) & (D_MODEL - 1);
  const int b = tid >> 14;
  const float ap = softplusf(a_log[e*D_STATE + s]) + 1e-4f;
  const float c2 = -ap * 1.44269504088896f;
  float S = 0.f;
  for (int c = 0; c < NCH; ++c) {
    const size_t ce  = ((size_t)c*BB + b)*D_MODEL + e;
    const size_t idx = ce*D_STATE + s;
    const float L  = Lc[idx];
    const float Ac = exp2f(c2 * dts[ce]);
    Lc[idx] = S;                 // exclusive prefix (chunk initial state)
    S = Ac*S + L;
  }
}

// ---------------- scan pass 3: recompute with carry-in, emit y (bf16) -------
__global__ __launch_bounds__(256) void scan_pass3_kernel(
    const float* __restrict__ x, const float* __restrict__ delta,
    const float* __restrict__ a_log, const float* __restrict__ b_param,
    const float* __restrict__ Lc, unsigned short* __restrict__ yb)
{
  const int e  = blockIdx.x * 256 + threadIdx.x;
  const int bc = blockIdx.y;
  const int b  = bc >> 6;
  const int c  = bc & (NCH-1);

  float c2[D_STATE], bp[D_STATE];
  #pragma unroll
  for (int s = 0; s < D_STATE; ++s) {
    const float ap = softplusf(a_log[e*D_STATE + s]) + 1e-4f;
    c2[s] = -ap * 1.44269504088896f;
    bp[s] = b_param[e*D_STATE + s];
  }
  const size_t ci = ((size_t)c*BB + b)*D_MODEL + e;
  float S[D_STATE];
  const float4* Lp = (const float4*)&Lc[ci*D_STATE];
  #pragma unroll
  for (int q = 0; q < 4; ++q) {
    float4 v = Lp[q];
    S[q*4+0] = v.x; S[q*4+1] = v.y; S[q*4+2] = v.z; S[q*4+3] = v.w;
  }
  const size_t base = ((size_t)b*TT + (size_t)c*CL)*D_MODEL + e;
  const float* xp = x + base;
  const float* dp = delta + base;
  for (int t = 0; t < CL; ++t) {
    const float dt = dp[(size_t)t*D_MODEL];
    const float xv = xp[(size_t)t*D_MODEL];
    const float u = dt * xv;
    float y = 0.f;
    #pragma unroll
    for (int s = 0; s < D_STATE; ++s) {
      S[s] = exp2f(c2[s]*dt) * S[s] + u;
      y += bp[s] * S[s];
    }
    yb[base + (size_t)t*D_MODEL] = f2bf(y);
  }
}

// ---------------------------------------------------------------------------
extern "C" void kernel_launch(void* const* d_in, const int* in_sizes, int n_in,
                              void* d_out, int out_size, void* d_ws, size_t ws_size,
                              hipStream_t stream)
{
  (void)in_sizes; (void)n_in; (void)out_size; (void)ws_size;
  const float* x       = (const float*)d_in[0];
  const float* Wd      = (const float*)d_in[1];
  const float* bd      = (const float*)d_in[2];
  const float* a_log   = (const float*)d_in[3];
  const float* b_param = (const float*)d_in[4];
  const float* Wo      = (const float*)d_in[5];
  const float* bo      = (const float*)d_in[6];
  float* out = (float*)d_out;

  // workspace layout (69 MB). Lc/dts alias xb: xb is dead after GEMM1,
  // Lc is written by pass1 which runs after GEMM1 on the same stream.
  char* ws = (char*)d_ws;
  unsigned short* xb  = (unsigned short*)(ws);              // 16 MB (bf16 x)
  float*          Lc  = (float*)(ws);                       // 16 MB (aliases xb)
  float*          dts = (float*)(ws + 16777216);            //  1 MB
  unsigned short* wdb = (unsigned short*)(ws + 17825792);   //  2 MB
  unsigned short* wob = (unsigned short*)(ws + 19922944);   //  2 MB
  float*          delta = (float*)(ws + 22020096);          // 32 MB
  unsigned short* yb  = (unsigned short*)(ws + 55574528);   // 16 MB
  // total: 72351744 bytes

  cvt_bf16_kernel<<<1024, 256, 0, stream>>>(x,  xb,  (MM*D_MODEL)/4);
  cvt_bf16_kernel<<<512,  256, 0, stream>>>(Wd, wdb, (D_MODEL*D_MODEL)/4);
  cvt_bf16_kernel<<<512,  256, 0, stream>>>(Wo, wob, (D_MODEL*D_MODEL)/4);

  gemm_bt_kernel<true><<<dim3(D_MODEL/128, MM/128), 256, 0, stream>>>(
      xb, wdb, bd, delta, MM, D_MODEL, D_MODEL);

  scan_pass1_kernel<<<dim3(D_MODEL/256, BB*NCH), 256, 0, stream>>>(
      x, delta, a_log, Lc, dts);
  scan_pass2_kernel<<<(BB*D_MODEL*D_STATE)/256, 256, 0, stream>>>(
      a_log, Lc, dts);
  scan_pass3_kernel<<<dim3(D_MODEL/256, BB*NCH), 256, 0, stream>>>(
      x, delta, a_log, b_param, Lc, yb);

  gemm_bt_kernel<false><<<dim3(D_MODEL/128, MM/128), 256, 0, stream>>>(
      yb, wob, bo, out, MM, D_MODEL, D_MODEL);
}

// Round 2
// 205.034 us; speedup vs baseline: 1.1130x; 1.1130x over previous
//
#include <hip/hip_runtime.h>
#include <stdint.h>

#define D_MODEL 1024
#define D_STATE 16
#define BB 4
#define TT 2048
#define MM (BB*TT)       /* 8192 rows */
#define NCH 64           /* time chunks */
#define CL (TT/NCH)      /* 32 steps per chunk */

typedef __attribute__((ext_vector_type(4))) float f32x4;
typedef __attribute__((ext_vector_type(8))) short short8;

__device__ __forceinline__ unsigned short f2bf(float f) {
  union { float f; uint32_t u; } v; v.f = f;
  uint32_t r = v.u + 0x7FFFu + ((v.u >> 16) & 1u);   // RNE
  return (unsigned short)(r >> 16);
}

__device__ __forceinline__ float softplusf(float v) {
  return v > 20.f ? v : log1pf(expf(v));
}

// ---------------- f32 -> bf16 conversion (float4 vectorized) ----------------
__global__ __launch_bounds__(256) void cvt_bf16_kernel(
    const float* __restrict__ in, unsigned short* __restrict__ out, int n4)
{
  const float4* in4 = (const float4*)in;
  ushort4* out4 = (ushort4*)out;
  int i = blockIdx.x * blockDim.x + threadIdx.x;
  const int stride = gridDim.x * blockDim.x;
  for (; i < n4; i += stride) {
    float4 v = in4[i];
    ushort4 o;
    o.x = f2bf(v.x); o.y = f2bf(v.y); o.z = f2bf(v.z); o.w = f2bf(v.w);
    out4[i] = o;
  }
}

// ---------------- bf16 GEMM, B^T layout: C[m][n] = sum_k A[m][k]*B[n][k] ----
// 128x128 tile, BK=64, 8 waves (2x4, each 64x32 out), double-buffered LDS with
// counted vmcnt(4) (T3/T4 2-phase), st_16x32 XOR swizzle (T2) applied to the
// pre-swizzled global source + ds_read address, XCD chunk swizzle (T1).
// N is assumed 1024 (8 n-tiles).
template<bool SOFTPLUS>
__device__ __forceinline__ void stage128x64(
    const unsigned short* __restrict__ A, const unsigned short* __restrict__ Bm,
    unsigned short* Al, unsigned short* Bl,
    int bm, int bn, int k0, int K, int tid)
{
  #pragma unroll
  for (int r = 0; r < 2; ++r) {
    const int wbase = r*8192 + ((tid >> 6) << 10);       // wave-uniform LDS byte base
    const int F     = wbase + (tid & 63)*16;             // per-lane linear byte
    const int row   = F >> 7;                            // 128B per row (64 bf16)
    const int col   = (F & 127) ^ (((F >> 9) & 1) << 5); // inverse(st_16x32) == st_16x32
    const size_t ga = ((size_t)(bm + row)*K + k0)*2 + col;
    const size_t gb = ((size_t)(bn + row)*K + k0)*2 + col;
    __builtin_amdgcn_global_load_lds(
        (const __attribute__((address_space(1))) void*)((const char*)A + ga),
        (__attribute__((address_space(3))) void*)((char*)Al + wbase), 16, 0, 0);
    __builtin_amdgcn_global_load_lds(
        (const __attribute__((address_space(1))) void*)((const char*)Bm + gb),
        (__attribute__((address_space(3))) void*)((char*)Bl + wbase), 16, 0, 0);
  }
}

template<bool SOFTPLUS>
__global__ __launch_bounds__(512, 4) void gemm_bt_kernel(
    const unsigned short* __restrict__ A,   // M x K bf16 (row-major)
    const unsigned short* __restrict__ Bm,  // N x K bf16 (row-major, i.e. B^T)
    const float* __restrict__ bias,         // N
    float* __restrict__ C,                  // M x N f32
    int M, int N, int K)
{
  __shared__ __align__(16) unsigned short Alds[2][128*64];  // 32 KB
  __shared__ __align__(16) unsigned short Blds[2][128*64];  // 32 KB
  const int tid  = threadIdx.x;
  const int lane = tid & 63;
  const int w    = tid >> 6;           // wave 0..7
  const int wr   = w >> 2, wc = w & 3; // 2 x 4 wave grid
  const int r16  = lane & 15, kh = lane >> 4;

  // T1: bijective XCD chunk swizzle (nwg % 8 == 0). XCD x gets a contiguous
  // chunk of m-tiles x all 8 n-tiles -> A panel (2MB) + B (2MB) fit its L2.
  const int nwg   = gridDim.x;
  const int flat  = blockIdx.x;
  const int newid = (flat & 7) * (nwg >> 3) + (flat >> 3);
  const int bm    = (newid >> 3) * 128;
  const int bn    = (newid & 7) * 128;

  f32x4 acc[4][2] = {};

  const int NT = K >> 6;    // 16
  stage128x64<SOFTPLUS>(A, Bm, Alds[0], Blds[0], bm, bn, 0, K, tid);

  for (int i = 0; i < NT; ++i) {
    if (i + 1 < NT) {
      stage128x64<SOFTPLUS>(A, Bm, Alds[(i+1)&1], Blds[(i+1)&1],
                            bm, bn, (i+1)*64, K, tid);
      asm volatile("s_waitcnt vmcnt(4)" ::: "memory");  // tile i's 4 loads done
    } else {
      asm volatile("s_waitcnt vmcnt(0)" ::: "memory");
    }
    __builtin_amdgcn_s_barrier();   // tile i visible to all waves

    const unsigned short* Ab = Alds[i & 1];
    const unsigned short* Bb = Blds[i & 1];
    short8 af[4][2], bf[2][2];
    #pragma unroll
    for (int m = 0; m < 4; ++m) {
      #pragma unroll
      for (int ks = 0; ks < 2; ++ks) {
        const int row = wr*64 + m*16 + r16;
        const int U = row*128 + ks*64 + kh*16;
        const int S = U ^ (((U >> 9) & 1) << 5);
        af[m][ks] = *(const short8*)((const char*)Ab + S);
      }
    }
    #pragma unroll
    for (int n = 0; n < 2; ++n) {
      #pragma unroll
      for (int ks = 0; ks < 2; ++ks) {
        const int row = wc*32 + n*16 + r16;
        const int U = row*128 + ks*64 + kh*16;
        const int S = U ^ (((U >> 9) & 1) << 5);
        bf[n][ks] = *(const short8*)((const char*)Bb + S);
      }
    }
    #pragma unroll
    for (int ks = 0; ks < 2; ++ks)
      #pragma unroll
      for (int m = 0; m < 4; ++m)
        #pragma unroll
        for (int n = 0; n < 2; ++n)
          acc[m][n] = __builtin_amdgcn_mfma_f32_16x16x32_bf16(af[m][ks], bf[n][ks], acc[m][n], 0, 0, 0);

    __builtin_amdgcn_s_barrier();   // reads of buf[i&1] done before overwrite
  }

  // epilogue: row = bm + wr*64 + m*16 + kh*4 + j ; col = bn + wc*32 + n*16 + r16
  #pragma unroll
  for (int n = 0; n < 2; ++n) {
    const int col = bn + wc*32 + n*16 + r16;
    const float bv = bias[col];
    #pragma unroll
    for (int m = 0; m < 4; ++m) {
      #pragma unroll
      for (int j = 0; j < 4; ++j) {
        const int row = bm + wr*64 + m*16 + kh*4 + j;
        float v = acc[m][n][j] + bv;
        if (SOFTPLUS) v = softplusf(v);
        C[(size_t)row*N + col] = v;
      }
    }
  }
}

// ---------------- scan pass 1: per-chunk local state L and sum(dt) ----------
__global__ __launch_bounds__(256) void scan_pass1_kernel(
    const float* __restrict__ x, const float* __restrict__ delta,
    const float* __restrict__ a_log,
    float* __restrict__ Lc, float* __restrict__ dts_out)
{
  const int e  = blockIdx.x * 256 + threadIdx.x;
  const int bc = blockIdx.y;
  const int b  = bc >> 6;            // NCH = 64
  const int c  = bc & (NCH-1);

  float c2[D_STATE];
  #pragma unroll
  for (int s = 0; s < D_STATE; ++s) {
    const float ap = softplusf(a_log[e*D_STATE + s]) + 1e-4f;
    c2[s] = -ap * 1.44269504088896f;   // -a_pos * log2(e)
  }
  const size_t base = ((size_t)b*TT + (size_t)c*CL)*D_MODEL + e;
  const float* xp = x + base;
  const float* dp = delta + base;
  float S[D_STATE] = {};
  float dts = 0.f;
  for (int t = 0; t < CL; ++t) {
    const float dt = dp[(size_t)t*D_MODEL];
    const float xv = xp[(size_t)t*D_MODEL];
    dts += dt;
    const float u = dt * xv;
    #pragma unroll
    for (int s = 0; s < D_STATE; ++s)
      S[s] = exp2f(c2[s]*dt) * S[s] + u;
  }
  const size_t ci = ((size_t)c*BB + b)*D_MODEL + e;
  dts_out[ci] = dts;
  float4* Lp = (float4*)&Lc[ci*D_STATE];
  #pragma unroll
  for (int q = 0; q < 4; ++q)
    Lp[q] = make_float4(S[q*4+0], S[q*4+1], S[q*4+2], S[q*4+3]);
}

// ---------------- scan pass 2: in-place exclusive scan over chunks ----------
__global__ __launch_bounds__(256) void scan_pass2_kernel(
    const float* __restrict__ a_log,
    float* __restrict__ Lc, const float* __restrict__ dts)
{
  const int tid = blockIdx.x * 256 + threadIdx.x;  // < 65536
  const int s = tid & 15;
  const int e = (tid >> 4) & (D_MODEL - 1);
  const int b = tid >> 14;
  const float ap = softplusf(a_log[e*D_STATE + s]) + 1e-4f;
  const float c2 = -ap * 1.44269504088896f;
  float S = 0.f;
  for (int c = 0; c < NCH; ++c) {
    const size_t ce  = ((size_t)c*BB + b)*D_MODEL + e;
    const size_t idx = ce*D_STATE + s;
    const float L  = Lc[idx];
    const float Ac = exp2f(c2 * dts[ce]);
    Lc[idx] = S;                 // exclusive prefix (chunk initial state)
    S = Ac*S + L;
  }
}

// ---------------- scan pass 3: recompute with carry-in, emit y (bf16) -------
__global__ __launch_bounds__(256) void scan_pass3_kernel(
    const float* __restrict__ x, const float* __restrict__ delta,
    const float* __restrict__ a_log, const float* __restrict__ b_param,
    const float* __restrict__ Lc, unsigned short* __restrict__ yb)
{
  const int e  = blockIdx.x * 256 + threadIdx.x;
  const int bc = blockIdx.y;
  const int b  = bc >> 6;
  const int c  = bc & (NCH-1);

  float c2[D_STATE], bp[D_STATE];
  #pragma unroll
  for (int s = 0; s < D_STATE; ++s) {
    const float ap = softplusf(a_log[e*D_STATE + s]) + 1e-4f;
    c2[s] = -ap * 1.44269504088896f;
    bp[s] = b_param[e*D_STATE + s];
  }
  const size_t ci = ((size_t)c*BB + b)*D_MODEL + e;
  float S[D_STATE];
  const float4* Lp = (const float4*)&Lc[ci*D_STATE];
  #pragma unroll
  for (int q = 0; q < 4; ++q) {
    float4 v = Lp[q];
    S[q*4+0] = v.x; S[q*4+1] = v.y; S[q*4+2] = v.z; S[q*4+3] = v.w;
  }
  const size_t base = ((size_t)b*TT + (size_t)c*CL)*D_MODEL + e;
  const float* xp = x + base;
  const float* dp = delta + base;
  for (int t = 0; t < CL; ++t) {
    const float dt = dp[(size_t)t*D_MODEL];
    const float xv = xp[(size_t)t*D_MODEL];
    const float u = dt * xv;
    float y = 0.f;
    #pragma unroll
    for (int s = 0; s < D_STATE; ++s) {
      S[s] = exp2f(c2[s]*dt) * S[s] + u;
      y += bp[s] * S[s];
    }
    yb[base + (size_t)t*D_MODEL] = f2bf(y);
  }
}

// ---------------------------------------------------------------------------
extern "C" void kernel_launch(void* const* d_in, const int* in_sizes, int n_in,
                              void* d_out, int out_size, void* d_ws, size_t ws_size,
                              hipStream_t stream)
{
  (void)in_sizes; (void)n_in; (void)out_size; (void)ws_size;
  const float* x       = (const float*)d_in[0];
  const float* Wd      = (const float*)d_in[1];
  const float* bd      = (const float*)d_in[2];
  const float* a_log   = (const float*)d_in[3];
  const float* b_param = (const float*)d_in[4];
  const float* Wo      = (const float*)d_in[5];
  const float* bo      = (const float*)d_in[6];
  float* out = (float*)d_out;

  // workspace layout (69 MB). Lc/dts alias xb: xb is dead after GEMM1.
  char* ws = (char*)d_ws;
  unsigned short* xb  = (unsigned short*)(ws);              // 16 MB (bf16 x)
  float*          Lc  = (float*)(ws);                       // 16 MB (aliases xb)
  float*          dts = (float*)(ws + 16777216);            //  1 MB
  unsigned short* wdb = (unsigned short*)(ws + 17825792);   //  2 MB
  unsigned short* wob = (unsigned short*)(ws + 19922944);   //  2 MB
  float*          delta = (float*)(ws + 22020096);          // 32 MB
  unsigned short* yb  = (unsigned short*)(ws + 55574528);   // 16 MB

  cvt_bf16_kernel<<<1024, 256, 0, stream>>>(x,  xb,  (MM*D_MODEL)/4);
  cvt_bf16_kernel<<<512,  256, 0, stream>>>(Wd, wdb, (D_MODEL*D_MODEL)/4);
  cvt_bf16_kernel<<<512,  256, 0, stream>>>(Wo, wob, (D_MODEL*D_MODEL)/4);

  gemm_bt_kernel<true><<<dim3((MM/128)*(D_MODEL/128)), 512, 0, stream>>>(
      xb, wdb, bd, delta, MM, D_MODEL, D_MODEL);

  scan_pass1_kernel<<<dim3(D_MODEL/256, BB*NCH), 256, 0, stream>>>(
      x, delta, a_log, Lc, dts);
  scan_pass2_kernel<<<(BB*D_MODEL*D_STATE)/256, 256, 0, stream>>>(
      a_log, Lc, dts);
  scan_pass3_kernel<<<dim3(D_MODEL/256, BB*NCH), 256, 0, stream>>>(
      x, delta, a_log, b_param, Lc, yb);

  gemm_bt_kernel<false><<<dim3((MM/128)*(D_MODEL/128)), 512, 0, stream>>>(
      yb, wob, bo, out, MM, D_MODEL, D_MODEL);
}

// Round 3
// 146.898 us; speedup vs baseline: 1.5535x; 1.3958x over previous
//
#include <hip/hip_runtime.h>
#include <stdint.h>

#define D_MODEL 1024
#define D_STATE 16
#define BB 4
#define TT 2048
#define MM (BB*TT)       /* 8192 rows */
#define NCH 64           /* time chunks */
#define CL (TT/NCH)      /* 32 steps per chunk */

typedef __attribute__((ext_vector_type(4))) float f32x4;
typedef __attribute__((ext_vector_type(8))) short short8;

__device__ __forceinline__ unsigned short f2bf(float f) {
  union { float f; uint32_t u; } v; v.f = f;
  uint32_t r = v.u + 0x7FFFu + ((v.u >> 16) & 1u);   // RNE
  return (unsigned short)(r >> 16);
}

__device__ __forceinline__ float softplusf(float v) {
  return v > 20.f ? v : log1pf(expf(v));
}

__device__ __forceinline__ f32x4 splat4(float s) {
  f32x4 r; r[0]=s; r[1]=s; r[2]=s; r[3]=s; return r;
}
__device__ __forceinline__ f32x4 exp2v4(f32x4 v) {
  f32x4 r;
  r[0]=__builtin_amdgcn_exp2f(v[0]);
  r[1]=__builtin_amdgcn_exp2f(v[1]);
  r[2]=__builtin_amdgcn_exp2f(v[2]);
  r[3]=__builtin_amdgcn_exp2f(v[3]);
  return r;
}

// ---------------- f32 -> bf16 conversion (float4 vectorized) ----------------
__global__ __launch_bounds__(256) void cvt_bf16_kernel(
    const float* __restrict__ in, unsigned short* __restrict__ out, int n4)
{
  const float4* in4 = (const float4*)in;
  ushort4* out4 = (ushort4*)out;
  int i = blockIdx.x * blockDim.x + threadIdx.x;
  const int stride = gridDim.x * blockDim.x;
  for (; i < n4; i += stride) {
    float4 v = in4[i];
    ushort4 o;
    o.x = f2bf(v.x); o.y = f2bf(v.y); o.z = f2bf(v.z); o.w = f2bf(v.w);
    out4[i] = o;
  }
}

// ---------------- precompute c2[e][s] = -(softplus(a_log)+1e-4)*log2e -------
__global__ __launch_bounds__(256) void prep_c2_kernel(
    const float* __restrict__ a_log, float* __restrict__ c2tab, int n)
{
  int i = blockIdx.x * 256 + threadIdx.x;
  if (i < n) {
    const float ap = softplusf(a_log[i]) + 1e-4f;
    c2tab[i] = -ap * 1.44269504088896f;
  }
}

// ---------------- bf16 GEMM, B^T layout: C[m][n] = sum_k A[m][k]*B[n][k] ----
// 128x128 tile, BK=64, 8 waves (2x4, each 64x32 out), double-buffered LDS with
// counted vmcnt(4), st_16x32 XOR swizzle, XCD chunk swizzle. N assumed 1024.
template<bool SOFTPLUS>
__device__ __forceinline__ void stage128x64(
    const unsigned short* __restrict__ A, const unsigned short* __restrict__ Bm,
    unsigned short* Al, unsigned short* Bl,
    int bm, int bn, int k0, int K, int tid)
{
  #pragma unroll
  for (int r = 0; r < 2; ++r) {
    const int wbase = r*8192 + ((tid >> 6) << 10);       // wave-uniform LDS byte base
    const int F     = wbase + (tid & 63)*16;             // per-lane linear byte
    const int row   = F >> 7;                            // 128B per row (64 bf16)
    const int col   = (F & 127) ^ (((F >> 9) & 1) << 5); // inverse(st_16x32) == st_16x32
    const size_t ga = ((size_t)(bm + row)*K + k0)*2 + col;
    const size_t gb = ((size_t)(bn + row)*K + k0)*2 + col;
    __builtin_amdgcn_global_load_lds(
        (const __attribute__((address_space(1))) void*)((const char*)A + ga),
        (__attribute__((address_space(3))) void*)((char*)Al + wbase), 16, 0, 0);
    __builtin_amdgcn_global_load_lds(
        (const __attribute__((address_space(1))) void*)((const char*)Bm + gb),
        (__attribute__((address_space(3))) void*)((char*)Bl + wbase), 16, 0, 0);
  }
}

template<bool SOFTPLUS>
__global__ __launch_bounds__(512, 4) void gemm_bt_kernel(
    const unsigned short* __restrict__ A,   // M x K bf16 (row-major)
    const unsigned short* __restrict__ Bm,  // N x K bf16 (row-major, i.e. B^T)
    const float* __restrict__ bias,         // N
    float* __restrict__ C,                  // M x N f32
    int M, int N, int K)
{
  __shared__ __align__(16) unsigned short Alds[2][128*64];  // 32 KB
  __shared__ __align__(16) unsigned short Blds[2][128*64];  // 32 KB
  const int tid  = threadIdx.x;
  const int lane = tid & 63;
  const int w    = tid >> 6;           // wave 0..7
  const int wr   = w >> 2, wc = w & 3; // 2 x 4 wave grid
  const int r16  = lane & 15, kh = lane >> 4;

  const int nwg   = gridDim.x;
  const int flat  = blockIdx.x;
  const int newid = (flat & 7) * (nwg >> 3) + (flat >> 3);
  const int bm    = (newid >> 3) * 128;
  const int bn    = (newid & 7) * 128;

  f32x4 acc[4][2] = {};

  const int NT = K >> 6;    // 16
  stage128x64<SOFTPLUS>(A, Bm, Alds[0], Blds[0], bm, bn, 0, K, tid);

  for (int i = 0; i < NT; ++i) {
    if (i + 1 < NT) {
      stage128x64<SOFTPLUS>(A, Bm, Alds[(i+1)&1], Blds[(i+1)&1],
                            bm, bn, (i+1)*64, K, tid);
      asm volatile("s_waitcnt vmcnt(4)" ::: "memory");  // tile i's 4 loads done
    } else {
      asm volatile("s_waitcnt vmcnt(0)" ::: "memory");
    }
    __builtin_amdgcn_s_barrier();   // tile i visible to all waves

    const unsigned short* Ab = Alds[i & 1];
    const unsigned short* Bb = Blds[i & 1];
    short8 af[4][2], bf[2][2];
    #pragma unroll
    for (int m = 0; m < 4; ++m) {
      #pragma unroll
      for (int ks = 0; ks < 2; ++ks) {
        const int row = wr*64 + m*16 + r16;
        const int U = row*128 + ks*64 + kh*16;
        const int S = U ^ (((U >> 9) & 1) << 5);
        af[m][ks] = *(const short8*)((const char*)Ab + S);
      }
    }
    #pragma unroll
    for (int n = 0; n < 2; ++n) {
      #pragma unroll
      for (int ks = 0; ks < 2; ++ks) {
        const int row = wc*32 + n*16 + r16;
        const int U = row*128 + ks*64 + kh*16;
        const int S = U ^ (((U >> 9) & 1) << 5);
        bf[n][ks] = *(const short8*)((const char*)Bb + S);
      }
    }
    #pragma unroll
    for (int ks = 0; ks < 2; ++ks)
      #pragma unroll
      for (int m = 0; m < 4; ++m)
        #pragma unroll
        for (int n = 0; n < 2; ++n)
          acc[m][n] = __builtin_amdgcn_mfma_f32_16x16x32_bf16(af[m][ks], bf[n][ks], acc[m][n], 0, 0, 0);

    __builtin_amdgcn_s_barrier();   // reads of buf[i&1] done before overwrite
  }

  #pragma unroll
  for (int n = 0; n < 2; ++n) {
    const int col = bn + wc*32 + n*16 + r16;
    const float bv = bias[col];
    #pragma unroll
    for (int m = 0; m < 4; ++m) {
      #pragma unroll
      for (int j = 0; j < 4; ++j) {
        const int row = bm + wr*64 + m*16 + kh*4 + j;
        float v = acc[m][n][j] + bv;
        if (SOFTPLUS) v = softplusf(v);
        C[(size_t)row*N + col] = v;
      }
    }
  }
}

// ---------------- scan pass 1: per-chunk local state L and sum(dt) ----------
// thread = (b, chunk, e); state in named f32x4 registers (no arrays).
__global__ __launch_bounds__(256) void scan_pass1_kernel(
    const float* __restrict__ x, const float* __restrict__ delta,
    const float* __restrict__ c2tab,
    float* __restrict__ Lc, float* __restrict__ dts_out)
{
  const int e  = blockIdx.x * 256 + threadIdx.x;
  const int b  = blockIdx.y >> 6;            // NCH = 64
  const int c  = blockIdx.y & (NCH-1);

  const f32x4* c2p = (const f32x4*)(c2tab + (size_t)e*D_STATE);
  const f32x4 c20=c2p[0], c21=c2p[1], c22=c2p[2], c23=c2p[3];

  f32x4 S0=splat4(0.f), S1=splat4(0.f), S2=splat4(0.f), S3=splat4(0.f);
  const size_t base = ((size_t)b*TT + (size_t)c*CL)*D_MODEL + e;
  const float* xp = x + base;
  const float* dp = delta + base;
  float dts = 0.f;
  #pragma unroll 4
  for (int t = 0; t < CL; ++t) {
    const float dt = dp[(size_t)t*D_MODEL];
    const float xv = xp[(size_t)t*D_MODEL];
    dts += dt;
    const f32x4 u4 = splat4(dt*xv);
    const f32x4 d4 = splat4(dt);
    S0 = exp2v4(c20*d4)*S0 + u4;
    S1 = exp2v4(c21*d4)*S1 + u4;
    S2 = exp2v4(c22*d4)*S2 + u4;
    S3 = exp2v4(c23*d4)*S3 + u4;
  }
  const size_t ci = ((size_t)c*BB + b)*D_MODEL + e;
  dts_out[ci] = dts;
  f32x4* Lp = (f32x4*)&Lc[ci*D_STATE];
  Lp[0]=S0; Lp[1]=S1; Lp[2]=S2; Lp[3]=S3;
}

// ---------------- scan pass 2: in-place exclusive scan over chunks ----------
__global__ __launch_bounds__(256) void scan_pass2_kernel(
    const float* __restrict__ c2tab,
    float* __restrict__ Lc, const float* __restrict__ dts)
{
  const int tid = blockIdx.x * 256 + threadIdx.x;  // < 65536
  const int e = (tid >> 4) & (D_MODEL - 1);
  const int b = tid >> 14;
  const float c2 = c2tab[tid & (D_MODEL*D_STATE - 1)];  // e*16 + s
  float S = 0.f;
  for (int c = 0; c < NCH; ++c) {
    const size_t ce  = ((size_t)c*BB + b)*D_MODEL + e;
    const size_t idx = ce*D_STATE + (tid & 15);
    const float L  = Lc[idx];
    const float Ac = __builtin_amdgcn_exp2f(c2 * dts[ce]);
    Lc[idx] = S;                 // exclusive prefix (chunk initial state)
    S = Ac*S + L;
  }
}

// ---------------- scan pass 3: recompute with carry-in, emit y (bf16) -------
__global__ __launch_bounds__(256) void scan_pass3_kernel(
    const float* __restrict__ x, const float* __restrict__ delta,
    const float* __restrict__ c2tab, const float* __restrict__ b_param,
    const float* __restrict__ Lc, unsigned short* __restrict__ yb)
{
  const int e  = blockIdx.x * 256 + threadIdx.x;
  const int b  = blockIdx.y >> 6;
  const int c  = blockIdx.y & (NCH-1);

  const f32x4* c2p = (const f32x4*)(c2tab + (size_t)e*D_STATE);
  const f32x4 c20=c2p[0], c21=c2p[1], c22=c2p[2], c23=c2p[3];
  const f32x4* bpp = (const f32x4*)(b_param + (size_t)e*D_STATE);
  const f32x4 bp0=bpp[0], bp1=bpp[1], bp2=bpp[2], bp3=bpp[3];

  const size_t ci = ((size_t)c*BB + b)*D_MODEL + e;
  const f32x4* Lp = (const f32x4*)&Lc[ci*D_STATE];
  f32x4 S0=Lp[0], S1=Lp[1], S2=Lp[2], S3=Lp[3];

  const size_t base = ((size_t)b*TT + (size_t)c*CL)*D_MODEL + e;
  const float* xp = x + base;
  const float* dp = delta + base;
  #pragma unroll 4
  for (int t = 0; t < CL; ++t) {
    const float dt = dp[(size_t)t*D_MODEL];
    const float xv = xp[(size_t)t*D_MODEL];
    const f32x4 u4 = splat4(dt*xv);
    const f32x4 d4 = splat4(dt);
    S0 = exp2v4(c20*d4)*S0 + u4;
    S1 = exp2v4(c21*d4)*S1 + u4;
    S2 = exp2v4(c22*d4)*S2 + u4;
    S3 = exp2v4(c23*d4)*S3 + u4;
    const f32x4 yv = bp0*S0 + bp1*S1 + bp2*S2 + bp3*S3;
    const float y = (yv[0]+yv[1]) + (yv[2]+yv[3]);
    yb[base + (size_t)t*D_MODEL] = f2bf(y);
  }
}

// ---------------------------------------------------------------------------
extern "C" void kernel_launch(void* const* d_in, const int* in_sizes, int n_in,
                              void* d_out, int out_size, void* d_ws, size_t ws_size,
                              hipStream_t stream)
{
  (void)in_sizes; (void)n_in; (void)out_size; (void)ws_size;
  const float* x       = (const float*)d_in[0];
  const float* Wd      = (const float*)d_in[1];
  const float* bd      = (const float*)d_in[2];
  const float* a_log   = (const float*)d_in[3];
  const float* b_param = (const float*)d_in[4];
  const float* Wo      = (const float*)d_in[5];
  const float* bo      = (const float*)d_in[6];
  float* out = (float*)d_out;

  // workspace layout (69 MB). Lc/dts alias xb: xb is dead after GEMM1.
  char* ws = (char*)d_ws;
  unsigned short* xb  = (unsigned short*)(ws);              // 16 MB (bf16 x)
  float*          Lc  = (float*)(ws);                       // 16 MB (aliases xb)
  float*          dts = (float*)(ws + 16777216);            //  1 MB
  unsigned short* wdb = (unsigned short*)(ws + 17825792);   //  2 MB
  unsigned short* wob = (unsigned short*)(ws + 19922944);   //  2 MB
  float*          delta = (float*)(ws + 22020096);          // 32 MB
  unsigned short* yb  = (unsigned short*)(ws + 55574528);   // 16 MB

  // c2 table (64 KB) lives at the head of d_out; every scan pass reads it
  // before GEMM2 fully overwrites d_out at the end. Deterministic each call.
  float* c2tab = (float*)d_out;

  prep_c2_kernel<<<(D_MODEL*D_STATE)/256, 256, 0, stream>>>(
      a_log, c2tab, D_MODEL*D_STATE);

  cvt_bf16_kernel<<<1024, 256, 0, stream>>>(x,  xb,  (MM*D_MODEL)/4);
  cvt_bf16_kernel<<<512,  256, 0, stream>>>(Wd, wdb, (D_MODEL*D_MODEL)/4);
  cvt_bf16_kernel<<<512,  256, 0, stream>>>(Wo, wob, (D_MODEL*D_MODEL)/4);

  gemm_bt_kernel<true><<<dim3((MM/128)*(D_MODEL/128)), 512, 0, stream>>>(
      xb, wdb, bd, delta, MM, D_MODEL, D_MODEL);

  scan_pass1_kernel<<<dim3(D_MODEL/256, BB*NCH), 256, 0, stream>>>(
      x, delta, c2tab, Lc, dts);
  scan_pass2_kernel<<<(BB*D_MODEL*D_STATE)/256, 256, 0, stream>>>(
      c2tab, Lc, dts);
  scan_pass3_kernel<<<dim3(D_MODEL/256, BB*NCH), 256, 0, stream>>>(
      x, delta, c2tab, b_param, Lc, yb);

  gemm_bt_kernel<false><<<dim3((MM/128)*(D_MODEL/128)), 512, 0, stream>>>(
      yb, wob, bo, out, MM, D_MODEL, D_MODEL);
}